// Round 5
// baseline (305.915 us; speedup 1.0000x reference)
//
#include <hip/hip_runtime.h>

// crossCorrelation3D: local (9x9x9) normalized cross-correlation loss, fused.
// B=2, C=1, D=H=W=160, fp32. Output = -mean(cc), scalar.
//
// R5: occupancy play. R0-R4 post-mortems: VALU~40%, LDS~45%, HBM~27%,
// Occupancy~39% across 5 structures -> stall-dominated, grid capacity-capped
// (1000 blocks = 3.9/CU co-resident; intra-block restructuring can't add
// concurrency).
//  1. DCHUNK 16 -> 2000 blocks = 7.8 blocks/CU.
//  2. LDS squeezed to 19584B (<20KB) so 8 blocks/CU fit -> ALL co-resident,
//     ~31 waves/CU (2x R3): single tmp5/Pb via 3-region pipeline
//     R:[ring+cc(l-2), stage(l)] X S:[prefetch(l+1), step2(l)] Y
//     T:[flow-load, hpass(l-1)] Z.  Hazards checked pairwise: every
//     producer/consumer pair crosses >=1 barrier.
//  3. OOB d-planes staged as zeros unconditionally (issue_load returns 0s)
//     -> no valid-branches; zero planes flow through step2/hpass/ring
//     matching zero-pad semantics.
//  4. __launch_bounds__(256,8): VGPR must stay <=64 for 8 waves/SIMD.
//     Single flv register (loaded in T, consumed next iter's R).
//
// NOTE: reference transforms target t=(raw+1)/2 BEFORE zero-padded box sum,
// so padding must contribute t=0. Transform applied at load time for
// in-bounds voxels only.

constexpr int NB = 2;
constexpr int ND = 160;
constexpr int NH = 160;
constexpr int NW = 160;
constexpr int TH = 16;
constexpr int TW = 16;
constexpr int DCHUNK = 16;
constexpr int NDCH = ND / DCHUNK;        // 10
constexpr int NPL = DCHUNK + 8;          // 24 planes staged per block
constexpr int NIT = NPL + 2;             // 26 pipeline iterations
constexpr int TRS = 20;                  // tmp5 row stride (floats, 80B)
constexpr int TFS = 24 * TRS + 4;        // 484: tmp5 field stride
constexpr int PRS = 16;                  // Pbuf row stride
constexpr int PFS = 16 * PRS + 8;        // 264: Pbuf field stride (mod 32 = 8)
constexpr float INV_K = 1.0f / 729.0f;
constexpr double INV_COUNT = 1.0 / (double(NB) * ND * NH * NW); // 1/8192000

// Issue global loads of one 24x24 halo plane (input & target) into registers.
// idx in [0,144): thread owns one float4 of the 24x(6*float4) plane. w0-4 is
// a multiple of 4 so rows are float4-aligned; each 4-wide segment is entirely
// in-bounds or entirely out (w0 % 16 == 0, halo = 4). OOB (d/h/w) -> zeros.
__device__ __forceinline__ void issue_load(
    const float* __restrict__ in, const float* __restrict__ tg,
    int b, int dp, int h0, int w0, int idx,
    float4& iv, float4& tv)
{
    iv = make_float4(0.f, 0.f, 0.f, 0.f);
    tv = make_float4(0.f, 0.f, 0.f, 0.f);
    if ((unsigned)idx < 144u && ((unsigned)dp < (unsigned)ND)) {
        int r = idx / 6;
        int q = idx - r * 6;
        int gh = h0 - 4 + r;
        int gw = w0 - 4 + q * 4;
        if (((unsigned)gh < (unsigned)NH) && ((unsigned)gw < (unsigned)NW)) {
            int base = ((b * ND + dp) * NH + gh) * NW + gw;   // fits int32
            iv = *reinterpret_cast<const float4*>(in + base);
            float4 rv = *reinterpret_cast<const float4*>(tg + base);
            tv.x = fmaf(rv.x, 0.5f, 0.5f);
            tv.y = fmaf(rv.y, 0.5f, 0.5f);
            tv.z = fmaf(rv.z, 0.5f, 0.5f);
            tv.w = fmaf(rv.w, 0.5f, 0.5f);
        }
    }
}

// w-direction 9-sums, quad form. Thread (r,q): outputs wo=4q..4q+3 of row r
// need inputs 4q..4q+11 (3 b128 per array). Register sliding per field.
#define W9SLIDE(EXPR, FI)                                                  \
    {                                                                      \
        float p0 = (EXPR(0)), p1 = (EXPR(1)), p2 = (EXPR(2)),              \
              p3 = (EXPR(3)), p4 = (EXPR(4)), p5 = (EXPR(5)),              \
              p6 = (EXPR(6)), p7 = (EXPR(7)), p8 = (EXPR(8)),              \
              p9 = (EXPR(9)), p10 = (EXPR(10)), p11 = (EXPR(11));          \
        float s = p0 + p1 + p2 + p3 + p4 + p5 + p6 + p7 + p8;              \
        float4 o;                                                          \
        o.x = s; s += p9 - p0;                                             \
        o.y = s; s += p10 - p1;                                            \
        o.z = s; s += p11 - p2;                                            \
        o.w = s;                                                           \
        *reinterpret_cast<float4*>(outp + (FI) * TFS) = o;                 \
    }

__device__ __forceinline__ void step2q(int tid, const float* __restrict__ inT,
                                       const float* __restrict__ tgT,
                                       float* __restrict__ t5)
{
    const int r = tid >> 2, q = tid & 3;
    const float4* ip = reinterpret_cast<const float4*>(inT + r * 24 + 4 * q);
    const float4* tp = reinterpret_cast<const float4*>(tgT + r * 24 + 4 * q);
    const float4 i0 = ip[0], i1 = ip[1], i2 = ip[2];
    const float4 t0 = tp[0], t1 = tp[1], t2 = tp[2];
    const float ia[12] = {i0.x, i0.y, i0.z, i0.w, i1.x, i1.y, i1.z, i1.w,
                          i2.x, i2.y, i2.z, i2.w};
    const float ta[12] = {t0.x, t0.y, t0.z, t0.w, t1.x, t1.y, t1.z, t1.w,
                          t2.x, t2.y, t2.z, t2.w};
    float* outp = t5 + r * TRS + 4 * q;
    #define E_T(j)  ta[j]
    #define E_I(j)  ia[j]
    #define E_TT(j) (ta[j] * ta[j])
    #define E_II(j) (ia[j] * ia[j])
    #define E_IT(j) (ia[j] * ta[j])
    W9SLIDE(E_T, 0)
    W9SLIDE(E_I, 1)
    W9SLIDE(E_TT, 2)
    W9SLIDE(E_II, 3)
    W9SLIDE(E_IT, 4)
    #undef E_T
    #undef E_I
    #undef E_TT
    #undef E_II
    #undef E_IT
}

// h-direction 9-sums, sliding quad form. t in [0,80): thread (f,wq,hs)
// produces ho=4hs..4hs+3 for field f, w-quad wq. Reads 12 rows as b128.
__device__ __forceinline__ void hpass(int t, const float* __restrict__ t5,
                                      float* __restrict__ Pb)
{
    const int f = t >> 4;
    const int rem = t & 15;
    const int wq = rem >> 2, hs = rem & 3;
    const float* bp = t5 + f * TFS + hs * 4 * TRS + wq * 4;
    float4 r4[12];
    #pragma unroll
    for (int k = 0; k < 12; ++k)
        r4[k] = *reinterpret_cast<const float4*>(bp + k * TRS);
    float sx = r4[0].x, sy = r4[0].y, sz = r4[0].z, sw = r4[0].w;
    #pragma unroll
    for (int k = 1; k < 9; ++k) {
        sx += r4[k].x; sy += r4[k].y; sz += r4[k].z; sw += r4[k].w;
    }
    float* op = Pb + f * PFS + hs * 4 * PRS + wq * 4;
    *reinterpret_cast<float4*>(op) = make_float4(sx, sy, sz, sw);
    #pragma unroll
    for (int j = 1; j < 4; ++j) {
        sx += r4[8 + j].x - r4[j - 1].x;
        sy += r4[8 + j].y - r4[j - 1].y;
        sz += r4[8 + j].z - r4[j - 1].z;
        sw += r4[8 + j].w - r4[j - 1].w;
        *reinterpret_cast<float4*>(op + j * PRS) = make_float4(sx, sy, sz, sw);
    }
}

__device__ __forceinline__ float cc_value(const float S[5], float flv)
{
    float wgt = 1.0f / (1.0f + __expf(-flv));   // sigmoid, GAMMA=1
    float Ts = S[0], Is = S[1], TTs = S[2], IIs = S[3], ITs = S[4];
    float Ihat = Is * INV_K;
    float That = Ts * INV_K;
    float cross = ITs - Ihat * Ts - That * Is + That * Ihat * 729.0f;
    float T_var = TTs - 2.0f * That * Ts + That * That * 729.0f;
    float I_var = IIs - 2.0f * Ihat * Is + Ihat * Ihat * 729.0f;
    return cross * cross * wgt / (T_var * I_var + 1e-5f);
}

__global__ void __launch_bounds__(256, 8)
cc3d_main(const float* __restrict__ in, const float* __restrict__ tg,
          const float* __restrict__ fl, double* __restrict__ acc_out)
{
    __shared__ __align__(16) float inT[24 * 24];
    __shared__ __align__(16) float tgT[24 * 24];
    __shared__ __align__(16) float tmp5[5 * TFS];
    __shared__ __align__(16) float Pb[5 * PFS];
    __shared__ float red[4];
    // LDS: (576+576+2420+1320+4)*4 = 19584 B  ->  8 blocks/CU

    const int tid = threadIdx.x;
    const int w0 = blockIdx.x * TW;
    const int h0 = blockIdx.y * TH;
    const int bz = blockIdx.z;
    const int b  = bz / NDCH;
    const int d0 = (bz - b * NDCH) * DCHUNK;
    const int hh = tid >> 4, ww = tid & 15;

    // D-direction ring of 9 plane values per field, statically indexed
    // (ring plane p = l-2; slot = p mod 9 = (li+7) mod 9, compile-time).
    float ring[45];
    #pragma unroll
    for (int i = 0; i < 45; ++i) ring[i] = 0.f;
    float S[5] = {0.f, 0.f, 0.f, 0.f, 0.f};
    float acc = 0.f;
    float flv = 0.f;

    // Prologue: loads for staged plane 0 (dp = d0-4) in flight.
    float4 civ, ctv;
    issue_load(in, tg, b, d0 - 4, h0, w0, tid, civ, ctv);

    // 3-region pipeline: iter l stages plane l, step2(l), hpass(l-1),
    // ring+cc(plane l-2; output when l>=10).  l = 0..NIT-1 (26 iters).
    for (int lb = 0; lb < NIT; lb += 9) {     // lb = 0,9,18
        #pragma unroll
        for (int li = 0; li < 9; ++li) {
            const int l = lb + li;
            if (l < NIT) {                    // block-uniform
                // ---- R: stage plane l (zeros if OOB); ring+cc plane l-2 ----
                if (l < NPL && tid < 144) {
                    reinterpret_cast<float4*>(inT)[tid] = civ;
                    reinterpret_cast<float4*>(tgT)[tid] = ctv;
                }
                if (l >= 2) {
                    const int slot = (li + 7) % 9;   // compile-time
                    #pragma unroll
                    for (int f = 0; f < 5; ++f) {
                        float pn = Pb[f * PFS + hh * PRS + ww];
                        S[f] += pn - ring[f * 9 + slot];
                        ring[f * 9 + slot] = pn;
                    }
                    if (l >= 10) acc += cc_value(S, flv);  // dout = d0+l-10
                }
                __syncthreads();              // X
                // ---- S: prefetch plane l+1 (issue first); step2 plane l ----
                float4 niv = make_float4(0.f, 0.f, 0.f, 0.f), ntv = niv;
                if (l + 1 < NPL)
                    issue_load(in, tg, b, d0 - 3 + l, h0, w0, tid, niv, ntv);
                if (l < NPL && tid < 96)
                    step2q(tid, inT, tgT, tmp5);
                __syncthreads();              // Y
                // ---- T: flow prefetch (for plane l-1's cc); hpass l-1 ----
                if (l >= 9 && l <= 24) {      // dout = d0 .. d0+15
                    int dout = d0 + l - 9;
                    flv = fl[((b * ND + dout) * NH + (h0 + hh)) * NW + (w0 + ww)];
                }
                if (l >= 1 && l <= NPL && tid < 80)
                    hpass(tid, tmp5, Pb);
                __syncthreads();              // Z
                civ = niv; ctv = ntv;
            }
        }
    }

    // ---- block reduction -> double atomic into workspace ----
    #pragma unroll
    for (int off = 32; off > 0; off >>= 1) acc += __shfl_down(acc, off);
    if ((tid & 63) == 0) red[tid >> 6] = acc;
    __syncthreads();
    if (tid == 0) {
        double v = (double)red[0] + (double)red[1] + (double)red[2] + (double)red[3];
        atomicAdd(acc_out, v);
    }
}

__global__ void cc3d_finalize(const double* __restrict__ acc, float* __restrict__ out)
{
    out[0] = (float)(-(acc[0] * INV_COUNT));
}

extern "C" void kernel_launch(void* const* d_in, const int* in_sizes, int n_in,
                              void* d_out, int out_size, void* d_ws, size_t ws_size,
                              hipStream_t stream)
{
    const float* in = (const float*)d_in[0];   // 'input'
    const float* tg = (const float*)d_in[1];   // 'target'
    const float* fl = (const float*)d_in[2];   // 'flow'
    float* out = (float*)d_out;
    double* acc = (double*)d_ws;

    hipMemsetAsync(d_ws, 0, sizeof(double), stream);  // graph-safe memset node

    dim3 grid(NW / TW, NH / TH, NB * NDCH);  // (10, 10, 20) = 2000 blocks
    cc3d_main<<<grid, dim3(256), 0, stream>>>(in, tg, fl, acc);
    cc3d_finalize<<<1, 1, 0, stream>>>(acc, out);
}

// Round 6
// 184.346 us; speedup vs baseline: 1.6595x; 1.6595x over previous
//
#include <hip/hip_runtime.h>

// crossCorrelation3D: local (9x9x9) normalized cross-correlation loss, fused.
// B=2, C=1, D=H=W=160, fp32. Output = -mean(cc), scalar.
//
// R6: R5's occupancy design minus the register catastrophe. R5 post-mortem:
// __launch_bounds__(256,8) forced a 64-VGPR cap -> allocator collapsed to 32
// VGPRs, spilled ring[45] to scratch (WRITE_SIZE 31KB->388MB, FETCH +230MB),
// VALUBusy 17.7%. BUT occupancy moved 39->84% proving the residency design
// (2000 blocks, LDS<20KB) works. R3/R4 compiled the same per-thread state to
// 60 VGPRs <= 64 = 512/8, so 8 waves/SIMD is reachable WITHOUT the cap: HW
// occupancy uses actual VGPR count, not the bound.
//  - DCHUNK 16 -> 2000 blocks = 7.8 blocks/CU, all co-resident at 8/CU.
//  - LDS 19584B (<20KB) -> 8 blocks/CU: single tmp5/Pb via 3-region pipeline
//    R:[stage(l), ring+cc(l-2)] X S:[prefetch(l+1), step2(l)] Y
//    T:[flow-load, hpass(l-1)] Z.  Hazards checked pairwise: every
//    producer/consumer pair crosses >=1 barrier.
//  - OOB d-planes staged as zeros unconditionally (matches zero-padding).
//  - __launch_bounds__(256,4): VGPR cap 128, compiler lands ~60 naturally.
//
// NOTE: reference transforms target t=(raw+1)/2 BEFORE zero-padded box sum,
// so padding must contribute t=0. Transform applied at load time for
// in-bounds voxels only.

constexpr int NB = 2;
constexpr int ND = 160;
constexpr int NH = 160;
constexpr int NW = 160;
constexpr int TH = 16;
constexpr int TW = 16;
constexpr int DCHUNK = 16;
constexpr int NDCH = ND / DCHUNK;        // 10
constexpr int NPL = DCHUNK + 8;          // 24 planes staged per block
constexpr int NIT = NPL + 2;             // 26 pipeline iterations
constexpr int TRS = 20;                  // tmp5 row stride (floats, 80B)
constexpr int TFS = 24 * TRS + 4;        // 484: tmp5 field stride
constexpr int PRS = 16;                  // Pbuf row stride
constexpr int PFS = 16 * PRS + 8;        // 264: Pbuf field stride (mod 32 = 8)
constexpr float INV_K = 1.0f / 729.0f;
constexpr double INV_COUNT = 1.0 / (double(NB) * ND * NH * NW); // 1/8192000

// Issue global loads of one 24x24 halo plane (input & target) into registers.
// idx in [0,144): thread owns one float4 of the 24x(6*float4) plane. w0-4 is
// a multiple of 4 so rows are float4-aligned; each 4-wide segment is entirely
// in-bounds or entirely out (w0 % 16 == 0, halo = 4). OOB (d/h/w) -> zeros.
__device__ __forceinline__ void issue_load(
    const float* __restrict__ in, const float* __restrict__ tg,
    int b, int dp, int h0, int w0, int idx,
    float4& iv, float4& tv)
{
    iv = make_float4(0.f, 0.f, 0.f, 0.f);
    tv = make_float4(0.f, 0.f, 0.f, 0.f);
    if ((unsigned)idx < 144u && ((unsigned)dp < (unsigned)ND)) {
        int r = idx / 6;
        int q = idx - r * 6;
        int gh = h0 - 4 + r;
        int gw = w0 - 4 + q * 4;
        if (((unsigned)gh < (unsigned)NH) && ((unsigned)gw < (unsigned)NW)) {
            int base = ((b * ND + dp) * NH + gh) * NW + gw;   // fits int32
            iv = *reinterpret_cast<const float4*>(in + base);
            float4 rv = *reinterpret_cast<const float4*>(tg + base);
            tv.x = fmaf(rv.x, 0.5f, 0.5f);
            tv.y = fmaf(rv.y, 0.5f, 0.5f);
            tv.z = fmaf(rv.z, 0.5f, 0.5f);
            tv.w = fmaf(rv.w, 0.5f, 0.5f);
        }
    }
}

// w-direction 9-sums, quad form. Thread (r,q): outputs wo=4q..4q+3 of row r
// need inputs 4q..4q+11 (3 b128 per array). Register sliding per field.
#define W9SLIDE(EXPR, FI)                                                  \
    {                                                                      \
        float p0 = (EXPR(0)), p1 = (EXPR(1)), p2 = (EXPR(2)),              \
              p3 = (EXPR(3)), p4 = (EXPR(4)), p5 = (EXPR(5)),              \
              p6 = (EXPR(6)), p7 = (EXPR(7)), p8 = (EXPR(8)),              \
              p9 = (EXPR(9)), p10 = (EXPR(10)), p11 = (EXPR(11));          \
        float s = p0 + p1 + p2 + p3 + p4 + p5 + p6 + p7 + p8;              \
        float4 o;                                                          \
        o.x = s; s += p9 - p0;                                             \
        o.y = s; s += p10 - p1;                                            \
        o.z = s; s += p11 - p2;                                            \
        o.w = s;                                                           \
        *reinterpret_cast<float4*>(outp + (FI) * TFS) = o;                 \
    }

__device__ __forceinline__ void step2q(int tid, const float* __restrict__ inT,
                                       const float* __restrict__ tgT,
                                       float* __restrict__ t5)
{
    const int r = tid >> 2, q = tid & 3;
    const float4* ip = reinterpret_cast<const float4*>(inT + r * 24 + 4 * q);
    const float4* tp = reinterpret_cast<const float4*>(tgT + r * 24 + 4 * q);
    const float4 i0 = ip[0], i1 = ip[1], i2 = ip[2];
    const float4 t0 = tp[0], t1 = tp[1], t2 = tp[2];
    const float ia[12] = {i0.x, i0.y, i0.z, i0.w, i1.x, i1.y, i1.z, i1.w,
                          i2.x, i2.y, i2.z, i2.w};
    const float ta[12] = {t0.x, t0.y, t0.z, t0.w, t1.x, t1.y, t1.z, t1.w,
                          t2.x, t2.y, t2.z, t2.w};
    float* outp = t5 + r * TRS + 4 * q;
    #define E_T(j)  ta[j]
    #define E_I(j)  ia[j]
    #define E_TT(j) (ta[j] * ta[j])
    #define E_II(j) (ia[j] * ia[j])
    #define E_IT(j) (ia[j] * ta[j])
    W9SLIDE(E_T, 0)
    W9SLIDE(E_I, 1)
    W9SLIDE(E_TT, 2)
    W9SLIDE(E_II, 3)
    W9SLIDE(E_IT, 4)
    #undef E_T
    #undef E_I
    #undef E_TT
    #undef E_II
    #undef E_IT
}

// h-direction 9-sums, sliding quad form. t in [0,80): thread (f,wq,hs)
// produces ho=4hs..4hs+3 for field f, w-quad wq. Reads 12 rows as b128.
__device__ __forceinline__ void hpass(int t, const float* __restrict__ t5,
                                      float* __restrict__ Pb)
{
    const int f = t >> 4;
    const int rem = t & 15;
    const int wq = rem >> 2, hs = rem & 3;
    const float* bp = t5 + f * TFS + hs * 4 * TRS + wq * 4;
    float4 r4[12];
    #pragma unroll
    for (int k = 0; k < 12; ++k)
        r4[k] = *reinterpret_cast<const float4*>(bp + k * TRS);
    float sx = r4[0].x, sy = r4[0].y, sz = r4[0].z, sw = r4[0].w;
    #pragma unroll
    for (int k = 1; k < 9; ++k) {
        sx += r4[k].x; sy += r4[k].y; sz += r4[k].z; sw += r4[k].w;
    }
    float* op = Pb + f * PFS + hs * 4 * PRS + wq * 4;
    *reinterpret_cast<float4*>(op) = make_float4(sx, sy, sz, sw);
    #pragma unroll
    for (int j = 1; j < 4; ++j) {
        sx += r4[8 + j].x - r4[j - 1].x;
        sy += r4[8 + j].y - r4[j - 1].y;
        sz += r4[8 + j].z - r4[j - 1].z;
        sw += r4[8 + j].w - r4[j - 1].w;
        *reinterpret_cast<float4*>(op + j * PRS) = make_float4(sx, sy, sz, sw);
    }
}

__device__ __forceinline__ float cc_value(const float S[5], float flv)
{
    float wgt = 1.0f / (1.0f + __expf(-flv));   // sigmoid, GAMMA=1
    float Ts = S[0], Is = S[1], TTs = S[2], IIs = S[3], ITs = S[4];
    float Ihat = Is * INV_K;
    float That = Ts * INV_K;
    float cross = ITs - Ihat * Ts - That * Is + That * Ihat * 729.0f;
    float T_var = TTs - 2.0f * That * Ts + That * That * 729.0f;
    float I_var = IIs - 2.0f * Ihat * Is + Ihat * Ihat * 729.0f;
    return cross * cross * wgt / (T_var * I_var + 1e-5f);
}

__global__ void __launch_bounds__(256, 4)
cc3d_main(const float* __restrict__ in, const float* __restrict__ tg,
          const float* __restrict__ fl, double* __restrict__ acc_out)
{
    __shared__ __align__(16) float inT[24 * 24];
    __shared__ __align__(16) float tgT[24 * 24];
    __shared__ __align__(16) float tmp5[5 * TFS];
    __shared__ __align__(16) float Pb[5 * PFS];
    __shared__ float red[4];
    // LDS: (576+576+2420+1320+4)*4 = 19584 B  ->  8 blocks/CU by LDS;
    // with VGPR<=64 the HW reaches 8 blocks/CU (32 waves).

    const int tid = threadIdx.x;
    const int w0 = blockIdx.x * TW;
    const int h0 = blockIdx.y * TH;
    const int bz = blockIdx.z;
    const int b  = bz / NDCH;
    const int d0 = (bz - b * NDCH) * DCHUNK;
    const int hh = tid >> 4, ww = tid & 15;

    // D-direction ring of 9 plane values per field, statically indexed
    // (ring plane p = l-2; slot = p mod 9 = (li+7) mod 9, compile-time).
    float ring[45];
    #pragma unroll
    for (int i = 0; i < 45; ++i) ring[i] = 0.f;
    float S[5] = {0.f, 0.f, 0.f, 0.f, 0.f};
    float acc = 0.f;
    float flv = 0.f;

    // Prologue: loads for staged plane 0 (dp = d0-4) in flight.
    float4 civ, ctv;
    issue_load(in, tg, b, d0 - 4, h0, w0, tid, civ, ctv);

    // 3-region pipeline: iter l stages plane l, step2(l), hpass(l-1),
    // ring+cc(plane l-2; output when l>=10).  l = 0..NIT-1 (26 iters).
    for (int lb = 0; lb < NIT; lb += 9) {     // lb = 0,9,18
        #pragma unroll
        for (int li = 0; li < 9; ++li) {
            const int l = lb + li;
            if (l < NIT) {                    // block-uniform
                // ---- R: stage plane l (zeros if OOB); ring+cc plane l-2 ----
                if (l < NPL && tid < 144) {
                    reinterpret_cast<float4*>(inT)[tid] = civ;
                    reinterpret_cast<float4*>(tgT)[tid] = ctv;
                }
                if (l >= 2) {
                    const int slot = (li + 7) % 9;   // compile-time
                    #pragma unroll
                    for (int f = 0; f < 5; ++f) {
                        float pn = Pb[f * PFS + hh * PRS + ww];
                        S[f] += pn - ring[f * 9 + slot];
                        ring[f * 9 + slot] = pn;
                    }
                    if (l >= 10) acc += cc_value(S, flv);  // dout = d0+l-10
                }
                __syncthreads();              // X
                // ---- S: prefetch plane l+1 (issue first); step2 plane l ----
                float4 niv = make_float4(0.f, 0.f, 0.f, 0.f), ntv = niv;
                if (l + 1 < NPL)
                    issue_load(in, tg, b, d0 - 3 + l, h0, w0, tid, niv, ntv);
                if (l < NPL && tid < 96)
                    step2q(tid, inT, tgT, tmp5);
                __syncthreads();              // Y
                // ---- T: flow prefetch (for plane l-1's cc); hpass l-1 ----
                if (l >= 9 && l <= 24) {      // dout = d0 .. d0+15
                    int dout = d0 + l - 9;
                    flv = fl[((b * ND + dout) * NH + (h0 + hh)) * NW + (w0 + ww)];
                }
                if (l >= 1 && l <= NPL && tid < 80)
                    hpass(tid, tmp5, Pb);
                __syncthreads();              // Z
                civ = niv; ctv = ntv;
            }
        }
    }

    // ---- block reduction -> double atomic into workspace ----
    #pragma unroll
    for (int off = 32; off > 0; off >>= 1) acc += __shfl_down(acc, off);
    if ((tid & 63) == 0) red[tid >> 6] = acc;
    __syncthreads();
    if (tid == 0) {
        double v = (double)red[0] + (double)red[1] + (double)red[2] + (double)red[3];
        atomicAdd(acc_out, v);
    }
}

__global__ void cc3d_finalize(const double* __restrict__ acc, float* __restrict__ out)
{
    out[0] = (float)(-(acc[0] * INV_COUNT));
}

extern "C" void kernel_launch(void* const* d_in, const int* in_sizes, int n_in,
                              void* d_out, int out_size, void* d_ws, size_t ws_size,
                              hipStream_t stream)
{
    const float* in = (const float*)d_in[0];   // 'input'
    const float* tg = (const float*)d_in[1];   // 'target'
    const float* fl = (const float*)d_in[2];   // 'flow'
    float* out = (float*)d_out;
    double* acc = (double*)d_ws;

    hipMemsetAsync(d_ws, 0, sizeof(double), stream);  // graph-safe memset node

    dim3 grid(NW / TW, NH / TH, NB * NDCH);  // (10, 10, 20) = 2000 blocks
    cc3d_main<<<grid, dim3(256), 0, stream>>>(in, tg, fl, acc);
    cc3d_finalize<<<1, 1, 0, stream>>>(acc, out);
}

// Round 7
// 173.954 us; speedup vs baseline: 1.7586x; 1.0597x over previous
//
#include <hip/hip_runtime.h>

// crossCorrelation3D: local (9x9x9) normalized cross-correlation loss, fused.
// B=2, C=1, D=H=W=160, fp32. Output = -mean(cc), scalar.
//
// R7: consolidation at the occupancy-tier ceiling.
// R5/R6 established the gfx950 VGPR tiers: v<=32 -> 8 waves/SIMD,
// v<=64 -> 4 waves/SIMD (R5: v=32 gave 84% occupancy; R6: v=64 gave 39%).
// ring[45]+S[5] state makes v<=32 unreachable without spills (R5: 388MB
// scratch traffic, strictly worse) -> ~16 waves/CU is the hard ceiling.
//  - DCHUNK 32: 1000 blocks ~= tier cap (4 blocks/CU), minimal total work.
//  - R3's VERIFIED plane alignment (absmax 0.0): tmp5 double-buffered,
//    hpass(l-1), ring adds plane l-2 at iter l, cc output j = l-10.
//  - 3-region pipeline (R6's faster per-plane structure, 2.02 ns/bp):
//    A:[stage(l), ring+cc(l-2)] X B:[prefetch(l+1), step2(l)] Y
//    C:[flow, hpass(l-1)] Z.  Hazards checked pairwise:
//      inT: w A(l), r B(l) (X between); overwritten A(l+1) after Y(l).
//      tmp5[l&1]: w B(l), r C(l+1); overwritten B(l+2) after C(l+1).
//      Pb: w C(l), r A(l+1) (Z between); prev read A(l) precedes C(l).
//  - Unconditional zero-plane flow for d-OOB planes (issue_load returns
//    zeros; zeros propagate through step2/hpass/ring exactly like the
//    reference's zero padding). No valid-branches; +3.8% plane work.
//
// NOTE: reference transforms target t=(raw+1)/2 BEFORE zero-padded box sum,
// so padding must contribute t=0. Transform applied at load time for
// in-bounds voxels only.

constexpr int NB = 2;
constexpr int ND = 160;
constexpr int NH = 160;
constexpr int NW = 160;
constexpr int TH = 16;
constexpr int TW = 16;
constexpr int DCHUNK = 32;
constexpr int NDCH = ND / DCHUNK;        // 5
constexpr int NPL = DCHUNK + 8;          // 40 planes staged per block
constexpr int NIT = NPL + 2;             // 42 pipeline iterations
constexpr int TRS = 20;                  // tmp5 row stride (floats, 80B)
constexpr int TFS = 24 * TRS + 4;        // 484: tmp5 field stride
constexpr int PRS = 16;                  // Pbuf row stride
constexpr int PFS = 16 * PRS + 8;        // 264: Pbuf field stride (mod 32 = 8)
constexpr float INV_K = 1.0f / 729.0f;
constexpr double INV_COUNT = 1.0 / (double(NB) * ND * NH * NW); // 1/8192000

// Issue global loads of one 24x24 halo plane (input & target) into registers.
// idx in [0,144): thread owns one float4 of the 24x(6*float4) plane. w0-4 is
// a multiple of 4 so rows are float4-aligned; each 4-wide segment is entirely
// in-bounds or entirely out (w0 % 16 == 0, halo = 4). OOB (d/h/w) -> zeros.
__device__ __forceinline__ void issue_load(
    const float* __restrict__ in, const float* __restrict__ tg,
    int b, int dp, int h0, int w0, int idx,
    float4& iv, float4& tv)
{
    iv = make_float4(0.f, 0.f, 0.f, 0.f);
    tv = make_float4(0.f, 0.f, 0.f, 0.f);
    if ((unsigned)idx < 144u && ((unsigned)dp < (unsigned)ND)) {
        int r = idx / 6;
        int q = idx - r * 6;
        int gh = h0 - 4 + r;
        int gw = w0 - 4 + q * 4;
        if (((unsigned)gh < (unsigned)NH) && ((unsigned)gw < (unsigned)NW)) {
            int base = ((b * ND + dp) * NH + gh) * NW + gw;   // fits int32
            iv = *reinterpret_cast<const float4*>(in + base);
            float4 rv = *reinterpret_cast<const float4*>(tg + base);
            tv.x = fmaf(rv.x, 0.5f, 0.5f);
            tv.y = fmaf(rv.y, 0.5f, 0.5f);
            tv.z = fmaf(rv.z, 0.5f, 0.5f);
            tv.w = fmaf(rv.w, 0.5f, 0.5f);
        }
    }
}

// w-direction 9-sums, quad form. Thread (r,q): outputs wo=4q..4q+3 of row r
// need inputs 4q..4q+11 (3 b128 per array). Register sliding per field.
#define W9SLIDE(EXPR, FI)                                                  \
    {                                                                      \
        float p0 = (EXPR(0)), p1 = (EXPR(1)), p2 = (EXPR(2)),              \
              p3 = (EXPR(3)), p4 = (EXPR(4)), p5 = (EXPR(5)),              \
              p6 = (EXPR(6)), p7 = (EXPR(7)), p8 = (EXPR(8)),              \
              p9 = (EXPR(9)), p10 = (EXPR(10)), p11 = (EXPR(11));          \
        float s = p0 + p1 + p2 + p3 + p4 + p5 + p6 + p7 + p8;              \
        float4 o;                                                          \
        o.x = s; s += p9 - p0;                                             \
        o.y = s; s += p10 - p1;                                            \
        o.z = s; s += p11 - p2;                                            \
        o.w = s;                                                           \
        *reinterpret_cast<float4*>(outp + (FI) * TFS) = o;                 \
    }

__device__ __forceinline__ void step2q(int tid, const float* __restrict__ inT,
                                       const float* __restrict__ tgT,
                                       float* __restrict__ t5)
{
    const int r = tid >> 2, q = tid & 3;
    const float4* ip = reinterpret_cast<const float4*>(inT + r * 24 + 4 * q);
    const float4* tp = reinterpret_cast<const float4*>(tgT + r * 24 + 4 * q);
    const float4 i0 = ip[0], i1 = ip[1], i2 = ip[2];
    const float4 t0 = tp[0], t1 = tp[1], t2 = tp[2];
    const float ia[12] = {i0.x, i0.y, i0.z, i0.w, i1.x, i1.y, i1.z, i1.w,
                          i2.x, i2.y, i2.z, i2.w};
    const float ta[12] = {t0.x, t0.y, t0.z, t0.w, t1.x, t1.y, t1.z, t1.w,
                          t2.x, t2.y, t2.z, t2.w};
    float* outp = t5 + r * TRS + 4 * q;
    #define E_T(j)  ta[j]
    #define E_I(j)  ia[j]
    #define E_TT(j) (ta[j] * ta[j])
    #define E_II(j) (ia[j] * ia[j])
    #define E_IT(j) (ia[j] * ta[j])
    W9SLIDE(E_T, 0)
    W9SLIDE(E_I, 1)
    W9SLIDE(E_TT, 2)
    W9SLIDE(E_II, 3)
    W9SLIDE(E_IT, 4)
    #undef E_T
    #undef E_I
    #undef E_TT
    #undef E_II
    #undef E_IT
}

// h-direction 9-sums, sliding quad form. t in [0,80): thread (f,wq,hs)
// produces ho=4hs..4hs+3 for field f, w-quad wq. Reads 12 rows as b128.
__device__ __forceinline__ void hpass(int t, const float* __restrict__ t5,
                                      float* __restrict__ Pb)
{
    const int f = t >> 4;
    const int rem = t & 15;
    const int wq = rem >> 2, hs = rem & 3;
    const float* bp = t5 + f * TFS + hs * 4 * TRS + wq * 4;
    float4 r4[12];
    #pragma unroll
    for (int k = 0; k < 12; ++k)
        r4[k] = *reinterpret_cast<const float4*>(bp + k * TRS);
    float sx = r4[0].x, sy = r4[0].y, sz = r4[0].z, sw = r4[0].w;
    #pragma unroll
    for (int k = 1; k < 9; ++k) {
        sx += r4[k].x; sy += r4[k].y; sz += r4[k].z; sw += r4[k].w;
    }
    float* op = Pb + f * PFS + hs * 4 * PRS + wq * 4;
    *reinterpret_cast<float4*>(op) = make_float4(sx, sy, sz, sw);
    #pragma unroll
    for (int j = 1; j < 4; ++j) {
        sx += r4[8 + j].x - r4[j - 1].x;
        sy += r4[8 + j].y - r4[j - 1].y;
        sz += r4[8 + j].z - r4[j - 1].z;
        sw += r4[8 + j].w - r4[j - 1].w;
        *reinterpret_cast<float4*>(op + j * PRS) = make_float4(sx, sy, sz, sw);
    }
}

__device__ __forceinline__ float cc_value(const float S[5], float flv)
{
    float wgt = 1.0f / (1.0f + __expf(-flv));   // sigmoid, GAMMA=1
    float Ts = S[0], Is = S[1], TTs = S[2], IIs = S[3], ITs = S[4];
    float Ihat = Is * INV_K;
    float That = Ts * INV_K;
    float cross = ITs - Ihat * Ts - That * Is + That * Ihat * 729.0f;
    float T_var = TTs - 2.0f * That * Ts + That * That * 729.0f;
    float I_var = IIs - 2.0f * Ihat * Is + Ihat * Ihat * 729.0f;
    return cross * cross * wgt / (T_var * I_var + 1e-5f);
}

__global__ void __launch_bounds__(256, 4)
cc3d_main(const float* __restrict__ in, const float* __restrict__ tg,
          const float* __restrict__ fl, double* __restrict__ acc_out)
{
    __shared__ __align__(16) float inT[24 * 24];
    __shared__ __align__(16) float tgT[24 * 24];
    __shared__ __align__(16) float tmp5[2][5 * TFS];
    __shared__ __align__(16) float Pb[5 * PFS];
    __shared__ float red[4];
    // LDS: (576*2 + 2*2420 + 1320 + 4)*4 = 29264 B -> LDS allows 5/CU,
    // VGPR tier (v in (32,64]) caps at 4 blocks/CU = 16 waves/CU.

    const int tid = threadIdx.x;
    const int w0 = blockIdx.x * TW;
    const int h0 = blockIdx.y * TH;
    const int bz = blockIdx.z;
    const int b  = bz / NDCH;
    const int d0 = (bz - b * NDCH) * DCHUNK;
    const int hh = tid >> 4, ww = tid & 15;

    // D-direction ring of 9 plane values per field, statically indexed.
    // At iter l the ring adds plane p = l-2; slot = p % 9 = (li+7) % 9
    // (compile-time inside the unrolled li loop since lb % 9 == 0).
    float ring[45];
    #pragma unroll
    for (int i = 0; i < 45; ++i) ring[i] = 0.f;
    float S[5] = {0.f, 0.f, 0.f, 0.f, 0.f};
    float acc = 0.f;
    float flv = 0.f, flv_next = 0.f;

    // Prologue: loads for plane 0 (dp = d0-4) in flight.
    float4 civ, ctv;
    issue_load(in, tg, b, d0 - 4, h0, w0, tid, civ, ctv);

    // 3-region pipeline: A:[stage(l), ring+cc(l-2)] X
    //                    B:[prefetch(l+1), step2(l)] Y
    //                    C:[flow, hpass(l-1)] Z
    for (int lb = 0; lb < NIT; lb += 9) {     // lb = 0,9,18,27,36
        #pragma unroll
        for (int li = 0; li < 9; ++li) {
            const int l = lb + li;
            if (l < NIT) {                    // block-uniform
                // ---- A: stage plane l; ring+cc plane l-2 ----
                if (l < NPL && tid < 144) {
                    reinterpret_cast<float4*>(inT)[tid] = civ;
                    reinterpret_cast<float4*>(tgT)[tid] = ctv;
                }
                if (l >= 2) {
                    const int slot = (li + 7) % 9;   // = (l-2) % 9
                    #pragma unroll
                    for (int f = 0; f < 5; ++f) {
                        float pn = Pb[f * PFS + hh * PRS + ww];
                        S[f] += pn - ring[f * 9 + slot];
                        ring[f * 9 + slot] = pn;
                    }
                    // window complete for output j = l-10 (planes j..j+8)
                    if (l >= 10) acc += cc_value(S, flv);
                }
                __syncthreads();              // X
                // ---- B: prefetch plane l+1 (issue first); step2 plane l ----
                float4 niv = make_float4(0.f, 0.f, 0.f, 0.f), ntv = niv;
                if (l + 1 < NPL)
                    issue_load(in, tg, b, d0 - 3 + l, h0, w0, tid, niv, ntv);
                if (l < NPL && tid < 96)
                    step2q(tid, inT, tgT, tmp5[l & 1]);
                __syncthreads();              // Y
                // ---- C: flow prefetch (for cc at A(l+1)); hpass plane l-1 ----
                if (l >= 9 && l <= 40) {      // dout = d0+l-9 in [d0, d0+31]
                    int dout = d0 + l - 9;
                    flv_next = fl[((b * ND + dout) * NH + (h0 + hh)) * NW + (w0 + ww)];
                }
                if (l >= 1 && l <= NPL && tid < 80)
                    hpass(tid, tmp5[(l - 1) & 1], Pb);
                __syncthreads();              // Z
                civ = niv; ctv = ntv; flv = flv_next;
            }
        }
    }

    // ---- block reduction -> double atomic into workspace ----
    #pragma unroll
    for (int off = 32; off > 0; off >>= 1) acc += __shfl_down(acc, off);
    if ((tid & 63) == 0) red[tid >> 6] = acc;
    __syncthreads();
    if (tid == 0) {
        double v = (double)red[0] + (double)red[1] + (double)red[2] + (double)red[3];
        atomicAdd(acc_out, v);
    }
}

__global__ void cc3d_finalize(const double* __restrict__ acc, float* __restrict__ out)
{
    out[0] = (float)(-(acc[0] * INV_COUNT));
}

extern "C" void kernel_launch(void* const* d_in, const int* in_sizes, int n_in,
                              void* d_out, int out_size, void* d_ws, size_t ws_size,
                              hipStream_t stream)
{
    const float* in = (const float*)d_in[0];   // 'input'
    const float* tg = (const float*)d_in[1];   // 'target'
    const float* fl = (const float*)d_in[2];   // 'flow'
    float* out = (float*)d_out;
    double* acc = (double*)d_ws;

    hipMemsetAsync(d_ws, 0, sizeof(double), stream);  // graph-safe memset node

    dim3 grid(NW / TW, NH / TH, NB * NDCH);  // (10, 10, 10) = 1000 blocks
    cc3d_main<<<grid, dim3(256), 0, stream>>>(in, tg, fl, acc);
    cc3d_finalize<<<1, 1, 0, stream>>>(acc, out);
}

// Round 8
// 169.124 us; speedup vs baseline: 1.8088x; 1.0286x over previous
//
#include <hip/hip_runtime.h>

// crossCorrelation3D: local (9x9x9) normalized cross-correlation loss, fused.
// B=2, C=1, D=H=W=160, fp32. Output = -mean(cc), scalar.
//
// R8: LDS-pipe is the bottleneck (R7 model: ~860/1230 cyc/iter = 70% busy,
// incl. 250 cyc conflicts). Three changes:
//  1. global_load_lds DMA staging (zero ds_writes, zero staging VGPRs, no
//     reg round-trip). Halo layout is lane-linear float4[144] = exactly the
//     HW's wave-uniform-base + lane*16 dest rule. Borders: exec-masked
//     lanes never write; pre-init inT=0, tgT=-1 (transform t=(raw+1)/2
//     moved into step2, so -1 border -> t=0 = zero-padding).
//  2. TFS 484->488 (mod 32 = 8): hpass-read bank slots become a perfect
//     (f,wq) 2-per-slot pairing -> even 8 lanes/slot (the one UNEVEN
//     pattern left; evenness, not spread, is the conflict criterion).
//  3. Single-buffered tmp5 (hpass(l) same iter as step2(l)): LDS 19.7KB.
// Pipeline (3 barriers, hazards pairwise-checked):
//   A: ring+cc(plane l-1, from Pb)    | X (drains DMA(l) -> inT ready)
//   B: step2(l): inT->tmp5            | Y
//   C: hpass(l): tmp5->Pb (tid>=176); DMA(l+1) (tid<144); flow | Z
//   inT: DMA issue C(l) lands <= Z(l) [barrier vmcnt drain], read B(l+1):
//        >=2 barriers. prev read B(l) before issue C(l): Y between.
//   tmp5: w B(l), r C(l): Y. next w B(l+1) after r C(l): Z,X.
//   Pb:   w C(l), r A(l+1): Z. next w C(l+1) after r A(l+1): X,Y.
// Alignment: ring adds plane p=l-1 at A(l); output j=l-9 (32 outputs,
// l in [9,40]); flow loaded C(l) for j=l-8 consumed A(l+1). d-OOB planes:
// step2/hpass/DMA skipped (block-uniform), ring substitutes pn=0.

constexpr int NB = 2;
constexpr int ND = 160;
constexpr int NH = 160;
constexpr int NW = 160;
constexpr int TH = 16;
constexpr int TW = 16;
constexpr int DCHUNK = 32;
constexpr int NDCH = ND / DCHUNK;        // 5
constexpr int NPL = DCHUNK + 8;          // 40 planes staged per block
constexpr int NIT = NPL + 1;             // 41 pipeline iterations
constexpr int TRS = 20;                  // tmp5 row stride (floats, 80B)
constexpr int TFS = 24 * TRS + 8;        // 488: mod 32 = 8 -> hpass reads even
constexpr int PRS = 16;                  // Pbuf row stride (ring reads 2-way free)
constexpr int PFS = 16 * PRS + 8;        // 264: mod 32 = 8 -> hpass writes even
constexpr float INV_K = 1.0f / 729.0f;
constexpr double INV_COUNT = 1.0 / (double(NB) * ND * NH * NW); // 1/8192000

__device__ __forceinline__ void gld_lds16(const float* g, float* l)
{
    __builtin_amdgcn_global_load_lds(
        (const __attribute__((address_space(1))) void*)g,
        (__attribute__((address_space(3))) void*)l, 16, 0, 0);
}

// DMA one 24x24 halo plane (input & raw target) into inT/tgT.
// Slot = tid (float4), lane-linear: per-wave uniform LDS base inT + wave*256
// floats; HW adds lane*16B. OOB (h/w) lanes exec-masked -> slots keep init
// values (0 / -1) forever (mask is d-independent). d-validity: caller.
// w0-4 mult of 4 -> 16B-aligned global src; 4-wide segments all-in or out.
__device__ __forceinline__ void dma_plane(const float* __restrict__ in,
                                          const float* __restrict__ tg,
                                          float* __restrict__ inT,
                                          float* __restrict__ tgT,
                                          int b, int dp, int h0, int w0, int tid)
{
    if (tid < 144) {
        int r = tid / 6;
        int q = tid - r * 6;
        int gh = h0 - 4 + r;
        int gw = w0 - 4 + q * 4;
        int wb = (tid >> 6) * 256;        // wave-uniform float offset
        if (((unsigned)gh < (unsigned)NH) && ((unsigned)gw < (unsigned)NW)) {
            int base = ((b * ND + dp) * NH + gh) * NW + gw;   // fits int32
            gld_lds16(in + base, inT + wb);
            gld_lds16(tg + base, tgT + wb);
        }
    }
}

// w-direction 9-sums, quad form. Thread (r,q): outputs wo=4q..4q+3 of row r
// need inputs 4q..4q+11 (3 b128 per array). Target transform applied HERE
// (tgT holds raw values; border slots = -1 -> t = 0 = zero padding).
#define W9SLIDE(EXPR, FI)                                                  \
    {                                                                      \
        float p0 = (EXPR(0)), p1 = (EXPR(1)), p2 = (EXPR(2)),              \
              p3 = (EXPR(3)), p4 = (EXPR(4)), p5 = (EXPR(5)),              \
              p6 = (EXPR(6)), p7 = (EXPR(7)), p8 = (EXPR(8)),              \
              p9 = (EXPR(9)), p10 = (EXPR(10)), p11 = (EXPR(11));          \
        float s = p0 + p1 + p2 + p3 + p4 + p5 + p6 + p7 + p8;              \
        float4 o;                                                          \
        o.x = s; s += p9 - p0;                                             \
        o.y = s; s += p10 - p1;                                            \
        o.z = s; s += p11 - p2;                                            \
        o.w = s;                                                           \
        *reinterpret_cast<float4*>(outp + (FI) * TFS) = o;                 \
    }

__device__ __forceinline__ void step2q(int tid, const float* __restrict__ inT,
                                       const float* __restrict__ tgT,
                                       float* __restrict__ t5)
{
    const int r = tid >> 2, q = tid & 3;
    const float4* ip = reinterpret_cast<const float4*>(inT + r * 24 + 4 * q);
    const float4* tp = reinterpret_cast<const float4*>(tgT + r * 24 + 4 * q);
    const float4 i0 = ip[0], i1 = ip[1], i2 = ip[2];
    const float4 t0 = tp[0], t1 = tp[1], t2 = tp[2];
    const float ia[12] = {i0.x, i0.y, i0.z, i0.w, i1.x, i1.y, i1.z, i1.w,
                          i2.x, i2.y, i2.z, i2.w};
    float ta[12] = {t0.x, t0.y, t0.z, t0.w, t1.x, t1.y, t1.z, t1.w,
                    t2.x, t2.y, t2.z, t2.w};
    #pragma unroll
    for (int j = 0; j < 12; ++j) ta[j] = fmaf(ta[j], 0.5f, 0.5f);
    float* outp = t5 + r * TRS + 4 * q;
    #define E_T(j)  ta[j]
    #define E_I(j)  ia[j]
    #define E_TT(j) (ta[j] * ta[j])
    #define E_II(j) (ia[j] * ia[j])
    #define E_IT(j) (ia[j] * ta[j])
    W9SLIDE(E_T, 0)
    W9SLIDE(E_I, 1)
    W9SLIDE(E_TT, 2)
    W9SLIDE(E_II, 3)
    W9SLIDE(E_IT, 4)
    #undef E_T
    #undef E_I
    #undef E_TT
    #undef E_II
    #undef E_IT
}

// h-direction 9-sums, sliding quad form. t in [0,80): thread (f,wq,hs)
// produces ho=4hs..4hs+3 for field f, w-quad wq. Reads 12 rows as b128.
__device__ __forceinline__ void hpass(int t, const float* __restrict__ t5,
                                      float* __restrict__ Pb)
{
    const int f = t >> 4;
    const int rem = t & 15;
    const int wq = rem >> 2, hs = rem & 3;
    const float* bp = t5 + f * TFS + hs * 4 * TRS + wq * 4;
    float4 r4[12];
    #pragma unroll
    for (int k = 0; k < 12; ++k)
        r4[k] = *reinterpret_cast<const float4*>(bp + k * TRS);
    float sx = r4[0].x, sy = r4[0].y, sz = r4[0].z, sw = r4[0].w;
    #pragma unroll
    for (int k = 1; k < 9; ++k) {
        sx += r4[k].x; sy += r4[k].y; sz += r4[k].z; sw += r4[k].w;
    }
    float* op = Pb + f * PFS + hs * 4 * PRS + wq * 4;
    *reinterpret_cast<float4*>(op) = make_float4(sx, sy, sz, sw);
    #pragma unroll
    for (int j = 1; j < 4; ++j) {
        sx += r4[8 + j].x - r4[j - 1].x;
        sy += r4[8 + j].y - r4[j - 1].y;
        sz += r4[8 + j].z - r4[j - 1].z;
        sw += r4[8 + j].w - r4[j - 1].w;
        *reinterpret_cast<float4*>(op + j * PRS) = make_float4(sx, sy, sz, sw);
    }
}

__device__ __forceinline__ float cc_value(const float S[5], float flv)
{
    float wgt = 1.0f / (1.0f + __expf(-flv));   // sigmoid, GAMMA=1
    float Ts = S[0], Is = S[1], TTs = S[2], IIs = S[3], ITs = S[4];
    float Ihat = Is * INV_K;
    float That = Ts * INV_K;
    float cross = ITs - Ihat * Ts - That * Is + That * Ihat * 729.0f;
    float T_var = TTs - 2.0f * That * Ts + That * That * 729.0f;
    float I_var = IIs - 2.0f * Ihat * Is + Ihat * Ihat * 729.0f;
    return cross * cross * wgt / (T_var * I_var + 1e-5f);
}

__global__ void __launch_bounds__(256, 4)
cc3d_main(const float* __restrict__ in, const float* __restrict__ tg,
          const float* __restrict__ fl, double* __restrict__ acc_out)
{
    __shared__ __align__(16) float inT[24 * 24];
    __shared__ __align__(16) float tgT[24 * 24];
    __shared__ __align__(16) float tmp5[5 * TFS];
    __shared__ __align__(16) float Pb[5 * PFS];
    __shared__ float red[4];
    // LDS: (576*2 + 5*488 + 5*264)*4 + 16 = 19664 B -> 8 blocks/CU by LDS.

    const int tid = threadIdx.x;
    const int w0 = blockIdx.x * TW;
    const int h0 = blockIdx.y * TH;
    const int bz = blockIdx.z;
    const int b  = bz / NDCH;
    const int d0 = (bz - b * NDCH) * DCHUNK;
    const int hh = tid >> 4, ww = tid & 15;

    // D-direction ring of 9 plane values per field. At iter l the ring adds
    // plane p = l-1; slot = p % 9 = (li+8) % 9 (compile-time, lb % 9 == 0).
    float ring[45];
    #pragma unroll
    for (int i = 0; i < 45; ++i) ring[i] = 0.f;
    float S[5] = {0.f, 0.f, 0.f, 0.f, 0.f};
    float acc = 0.f;
    float flv = 0.f;

    // Init halo arrays: border slots (exec-masked in DMA) must read as
    // padding forever: input 0, raw target -1 (-> transformed t = 0).
    for (int i = tid; i < 576; i += 256) { inT[i] = 0.f; tgT[i] = -1.f; }
    __syncthreads();
    // Prologue: DMA plane 0 (dp = d0-4); skipped when d-OOB (d0 = 0).
    if (d0 - 4 >= 0) dma_plane(in, tg, inT, tgT, b, d0 - 4, h0, w0, tid);

    for (int lb = 0; lb < NIT; lb += 9) {     // lb = 0,9,18,27,36
        #pragma unroll
        for (int li = 0; li < 9; ++li) {
            const int l = lb + li;
            if (l < NIT) {                    // block-uniform
                // ---- A: ring+cc for plane p = l-1 (Pb written at C(l-1)) ----
                if (l >= 1) {
                    const bool vz = ((unsigned)(d0 - 5 + l) < (unsigned)ND);
                    const int slot = (li + 8) % 9;   // compile-time
                    #pragma unroll
                    for (int f = 0; f < 5; ++f) {
                        float pn = vz ? Pb[f * PFS + hh * PRS + ww] : 0.f;
                        S[f] += pn - ring[f * 9 + slot];
                        ring[f * 9 + slot] = pn;
                    }
                    if (l >= 9) acc += cc_value(S, flv);   // j = l-9
                }
                __syncthreads();              // X (drains DMA(l); inT ready)
                // ---- B: step2 plane l ----
                const int dpl = d0 - 4 + l;
                const bool vl = (l < NPL) && ((unsigned)dpl < (unsigned)ND);
                if (vl && tid < 96) step2q(tid, inT, tgT, tmp5);
                __syncthreads();              // Y
                // ---- C: hpass(l) [tid>=176]; DMA(l+1) [tid<144]; flow ----
                if (vl && tid >= 176) hpass(tid - 176, tmp5, Pb);
                if (l + 1 < NPL && (unsigned)(dpl + 1) < (unsigned)ND)
                    dma_plane(in, tg, inT, tgT, b, dpl + 1, h0, w0, tid);
                if (l >= 8 && l < 40) {       // flv for A(l+1): j = l-8
                    int dout = d0 + l - 8;
                    flv = fl[((b * ND + dout) * NH + (h0 + hh)) * NW + (w0 + ww)];
                }
                __syncthreads();              // Z (drains DMA(l+1) + flv)
            }
        }
    }

    // ---- block reduction -> double atomic into workspace ----
    #pragma unroll
    for (int off = 32; off > 0; off >>= 1) acc += __shfl_down(acc, off);
    if ((tid & 63) == 0) red[tid >> 6] = acc;
    __syncthreads();
    if (tid == 0) {
        double v = (double)red[0] + (double)red[1] + (double)red[2] + (double)red[3];
        atomicAdd(acc_out, v);
    }
}

__global__ void cc3d_finalize(const double* __restrict__ acc, float* __restrict__ out)
{
    out[0] = (float)(-(acc[0] * INV_COUNT));
}

extern "C" void kernel_launch(void* const* d_in, const int* in_sizes, int n_in,
                              void* d_out, int out_size, void* d_ws, size_t ws_size,
                              hipStream_t stream)
{
    const float* in = (const float*)d_in[0];   // 'input'
    const float* tg = (const float*)d_in[1];   // 'target'
    const float* fl = (const float*)d_in[2];   // 'flow'
    float* out = (float*)d_out;
    double* acc = (double*)d_ws;

    hipMemsetAsync(d_ws, 0, sizeof(double), stream);  // graph-safe memset node

    dim3 grid(NW / TW, NH / TH, NB * NDCH);  // (10, 10, 10) = 1000 blocks
    cc3d_main<<<grid, dim3(256), 0, stream>>>(in, tg, fl, acc);
    cc3d_finalize<<<1, 1, 0, stream>>>(acc, out);
}